// Round 7
// baseline (543.256 us; speedup 1.0000x reference)
//
#include <hip/hip_runtime.h>
#include <cstdint>

typedef unsigned short u16;
typedef unsigned int   u32;
typedef unsigned long long u64;

typedef _Float16 f16x2 __attribute__((ext_vector_type(2)));
typedef _Float16 f16x8 __attribute__((ext_vector_type(8)));
typedef float    f32x4 __attribute__((ext_vector_type(4)));

// pack two f32 into fp16x2 bits (RTZ fine: inputs exactly fp16-representable)
__device__ __forceinline__ u32 cvt_pk(float a, float b) {
    return __builtin_bit_cast(u32, __builtin_amdgcn_cvt_pkrtz(a, b));
}

// Unpack one int32 (8 nibbles LSB-first along K) -> dequantized f16x8 in the
// k-order [0,4,1,5,2,6,3,7]. Exact math, verified R1-R6 (absmax 0.0625).
__device__ __forceinline__ f16x8 unpack_dq(u32 q, f16x2 cz, f16x2 cs) {
    const u32 b0 = (q & 0x000F000Fu) | 0x64006400u;         // nib0,nib4
    const u32 b1 = ((q >> 4) & 0x000F000Fu) | 0x64006400u;  // nib1,nib5
    const u32 b2 = ((q >> 8) & 0x000F000Fu) | 0x64006400u;  // nib2,nib6
    const u32 b3 = ((q >> 12) & 0x000F000Fu) | 0x64006400u; // nib3,nib7
    const f16x2 w0 = (__builtin_bit_cast(f16x2, b0) - cz) * cs;
    const f16x2 w1 = (__builtin_bit_cast(f16x2, b1) - cz) * cs;
    const f16x2 w2 = (__builtin_bit_cast(f16x2, b2) - cz) * cs;
    const f16x2 w3 = (__builtin_bit_cast(f16x2, b3) - cz) * cs;
    uint4 w;
    w.x = __builtin_bit_cast(u32, w0);
    w.y = __builtin_bit_cast(u32, w1);
    w.z = __builtin_bit_cast(u32, w2);
    w.w = __builtin_bit_cast(u32, w3);
    return __builtin_bit_cast(f16x8, w);
}

__device__ __forceinline__ void load_lds16(const void* g, void* l) {
    __builtin_amdgcn_global_load_lds(
        (const __attribute__((address_space(1))) void*)g,
        (__attribute__((address_space(3))) void*)l,
        16, 0, 0);
}

// =====================================================================
// Prepass A: X f32 [8192,4096] -> Xh f16, tiled LDS-image layout.
// (unchanged) Tile byte image: u16 off = r*64 + sg*8, sg = g ^ (r&7),
// granule g holds k-local [8g,8g+8) in order [0,4,1,5,2,6,3,7].
// =====================================================================
__global__ __launch_bounds__(256) void gptq_prepass(
    const float* __restrict__ X, u16* __restrict__ Xh)
{
    const u32 tile = blockIdx.x;          // 0..4095 : mt = tile>>6, t = tile&63
    const u32 mt = tile >> 6, t = tile & 63;
    const float* bsrc = X + ((u64)mt << 19) + t * 64;   // mt*128 rows * 4096
    u16* bdst = Xh + ((u64)tile << 13);                 // tile * 8192 u16
#pragma unroll
    for (int pass = 0; pass < 4; ++pass) {
        const u32 idx = pass * 256 + threadIdx.x;       // 0..1023
        const u32 r = idx >> 3, sg = idx & 7, g = sg ^ (r & 7);
        const float* s = bsrc + ((u64)r << 12) + g * 8;
        const float4 f0 = *(const float4*)s;
        const float4 f1 = *(const float4*)(s + 4);
        uint4 w;
        w.x = cvt_pk(f0.x, f1.x);
        w.y = cvt_pk(f0.y, f1.y);
        w.z = cvt_pk(f0.z, f1.z);
        w.w = cvt_pk(f0.w, f1.w);
        *(uint4*)(bdst + idx * 8) = w;                  // contiguous per pass
    }
}

// =====================================================================
// Prepass B: transpose QW [4096,512] -> QWt [512,4096] (k-major).
// (unchanged, measured win) Coalesced GEMM B-loads.
// =====================================================================
__global__ __launch_bounds__(256) void gptq_transpose(
    const int* __restrict__ QW, int* __restrict__ QWt)
{
    __shared__ int tile[64][65];          // +1 pad: conflict-free columns
    const u32 bkq = blockIdx.x;           // 0..7   (kq block)
    const u32 bn  = blockIdx.y;           // 0..63  (n block)
    const u32 t = threadIdx.x;
    const u32 r = t >> 4, c4 = (t & 15) * 4;
#pragma unroll
    for (int p = 0; p < 4; ++p) {
        const u32 row = p * 16 + r;       // n-local
        const int4 v = *(const int4*)(QW + (u64)(bn * 64 + row) * 512
                                         + bkq * 64 + c4);
        tile[row][c4 + 0] = v.x; tile[row][c4 + 1] = v.y;
        tile[row][c4 + 2] = v.z; tile[row][c4 + 3] = v.w;
    }
    __syncthreads();
#pragma unroll
    for (int p = 0; p < 4; ++p) {
        const u32 kql = p * 16 + r;       // kq-local
        int4 v;
        v.x = tile[c4 + 0][kql]; v.y = tile[c4 + 1][kql];
        v.z = tile[c4 + 2][kql]; v.w = tile[c4 + 3][kql];
        *(int4*)(QWt + (u64)(bkq * 64 + kql) * 4096 + bn * 64 + c4) = v;
    }
}

// =====================================================================
// Main GEMM: R6's measured structure (counted vmcnt, raw barriers,
// setprio, QWt coalesced B, ks*4+quad chunk map) retiled for occupancy:
// wave tile 128x64 -> 64x64 (acc[4][4], 64 AGPR) => 3 blocks/CU,
// 3 waves/SIMD. Block 128x128 (2x2 waves), grid 64x32.
// =====================================================================
__global__ __launch_bounds__(256, 3) void gptq_gemm_dma(
    const u16* __restrict__ Xh,     // [M/128][K/64][128][64] f16, swizzled
    const int* __restrict__ QWt,    // [K/8, N] int32, k-major
    const int* __restrict__ QZ,     // [G, N/8] int32
    const float* __restrict__ SC,   // [G, N] f32
    const float* __restrict__ BIAS, // [N] f32
    float* __restrict__ Y)          // [M, N] f32
{
    constexpr int N = 4096, NT = 64;

    __shared__ __align__(16) u16 Alds[2][128 * 64];   // 2 x 16 KB, A only

    const int tid  = threadIdx.x;
    const int lane = tid & 63;
    const int wid  = tid >> 6;
    const int wm   = (wid >> 1) * 64;    // wave m-offset in 128-row tile
    const int wnq  = (wid & 1) * 64;     // wave n-offset in 128-col tile

    const int mt = blockIdx.x;       // 0..63
    const int m0 = mt * 128;
    const int n0 = blockIdx.y * 128; // gridDim.y = 32

    f32x4 acc[4][4];
#pragma unroll
    for (int i = 0; i < 4; i++)
#pragma unroll
        for (int j = 0; j < 4; j++)
            acc[i][j] = (f32x4){0.f, 0.f, 0.f, 0.f};

    // MFMA fragment indices
    const int fr   = lane & 15;
    const int quad = lane >> 4;
    const int fr7  = fr & 7;

    // A staging: per-lane global source (layout == LDS image), linear LDS dest
    const char* xsrc = (const char*)Xh + (((u64)mt * NT) << 14)
                     + wid * 4096 + lane * 16;

    // B from QWt: chunk c=ks*4+quad -> kq = t*8 + quad (+4 for ks=1).
    // byte addr = ((t*8+quad+ks*4)*4096 + n) * 4; per-quad 16 lanes read
    // 64 contiguous bytes. K-step stride = 8*4096*4 = 1<<17.
    const int nbase = n0 + wnq + fr;
    const char* QWtB = (const char*)QWt;
    const u64 qtbase = (u64)((u32)(quad * 4096 + nbase) * 4u);

    int   bq[2][8];           // [nb][ni*2+ks], static indices only
    float sf_st[4];
    int   zw_st[4];
    f16x2 cs[4], cz[4];
    const int zsh = fr7 * 4;

    auto STAGE = [&](int buf, int t) {                  // 4 DMA loads
        const char* s = xsrc + ((u64)t << 14);
        char* d = (char*)&Alds[buf][0] + wid * 4096;
#pragma unroll
        for (int i = 0; i < 4; i++)
            load_lds16(s + i * 1024, d + i * 1024);
    };

    auto FETCH_B = [&](int t, int nb) {                 // 8 coalesced dwords
        const char* p = QWtB + ((u64)t << 17) + qtbase;
#pragma unroll
        for (int ni = 0; ni < 4; ni++) {
            bq[nb][ni * 2 + 0] = *(const int*)(p + ni * 64);
            bq[nb][ni * 2 + 1] = *(const int*)(p + 65536 + ni * 64);
        }
    };

    auto FETCH_SZ = [&](int g) {                        // 8 dword loads
#pragma unroll
        for (int ni = 0; ni < 4; ni++) {
            sf_st[ni] = SC[g * N + nbase + ni * 16];
            zw_st[ni] = QZ[g * (N / 8) + ((nbase + ni * 16) >> 3)];
        }
    };

    auto CONV_SZ = [&]() {
#pragma unroll
        for (int ni = 0; ni < 4; ni++) {
            const int z = (zw_st[ni] >> zsh) & 0xF;
            const _Float16 hs = (_Float16)sf_st[ni];
            const _Float16 hz = (_Float16)(float)(1024 + z);
            cs[ni] = (f16x2){hs, hs};
            cz[ni] = (f16x2){hz, hz};
        }
    };

    auto COMPUTE = [&](int buf, int nb) {
#pragma unroll
        for (int ks = 0; ks < 2; ks++) {
            f16x8 bfr[4];
#pragma unroll
            for (int ni = 0; ni < 4; ni++)
                bfr[ni] = unpack_dq((u32)bq[nb][ni * 2 + ks], cz[ni], cs[ni]);
            const int gsw = ((ks * 4 + quad) ^ fr7) * 8;
            __builtin_amdgcn_s_setprio(1);
#pragma unroll
            for (int mi = 0; mi < 4; mi++) {
                const f16x8 af =
                    *(const f16x8*)(&Alds[buf][(wm + mi * 16 + fr) * 64 + gsw]);
#pragma unroll
                for (int ni = 0; ni < 4; ni++)
                    acc[mi][ni] = __builtin_amdgcn_mfma_f32_16x16x32_f16(
                        af, bfr[ni], acc[mi][ni], 0, 0, 0);
            }
            __builtin_amdgcn_s_setprio(0);
        }
    };

    // ---- prologue: B(0):8, SZ(0):8, STAGE(0):4, STAGE(1):4 ----
    FETCH_B(0, 0);
    FETCH_SZ(0);
    STAGE(0, 0);
    STAGE(1, 1);
    CONV_SZ();
    // allow STAGE(1)'s 4 to stay in flight; tile 0 guaranteed landed
    asm volatile("s_waitcnt vmcnt(4)\n\ts_barrier" ::: "memory");

    // ---- main loop: 31 pairs, counted vmcnt, no drain-to-0 ----
    for (int t = 0; t <= 60; t += 2) {
        // even: compute tile t (buf0)
        FETCH_B(t + 1, 1);               // 8
        FETCH_SZ((t >> 1) + 1);          // 8  (g+1 <= 31 always here)
        COMPUTE(0, 0);
        asm volatile("s_barrier" ::: "memory");          // buf0 free
        STAGE(0, t + 2);                 // 4 DMA
        // ensure STAGE(t+1) landed; newer ops = B8 + SZ8 + STAGE4 = 20
        asm volatile("s_waitcnt vmcnt(20)\n\ts_barrier" ::: "memory");

        // odd: compute tile t+1 (buf1)
        FETCH_B(t + 2, 0);               // 8
        COMPUTE(1, 1);
        CONV_SZ();                       // constants for group (t>>1)+1
        asm volatile("s_barrier" ::: "memory");          // buf1 free
        STAGE(1, t + 3);                 // 4 DMA
        // ensure STAGE(t+2) landed; newer ops = B8 + STAGE4 = 12
        asm volatile("s_waitcnt vmcnt(12)\n\ts_barrier" ::: "memory");
    }

    // ---- tail: tiles 62, 63 (already staged), no more staging ----
    FETCH_B(63, 1);                      // 8
    COMPUTE(0, 0);                       // tile 62
    // ensure STAGE(63) landed; newer ops = B(63):8
    asm volatile("s_waitcnt vmcnt(8)\n\ts_barrier" ::: "memory");
    COMPUTE(1, 1);                       // tile 63

    // ---- epilogue: + bias. C/D map: col=lane&15, row=quad*4+reg ----
    const int cn  = lane & 15;
    const int q4r = quad * 4;
#pragma unroll
    for (int ni = 0; ni < 4; ni++) {
        const int col = n0 + wnq + ni * 16 + cn;
        const float bz = BIAS[col];
#pragma unroll
        for (int mi = 0; mi < 4; mi++) {
            const int rbase = m0 + wm + mi * 16 + q4r;
#pragma unroll
            for (int r = 0; r < 4; r++) {
                Y[(u64)(rbase + r) * N + col] = acc[mi][ni][r] + bz;
            }
        }
    }
}

// =====================================================================
// Fallback (ws too small): R1's verified kernel, unchanged (uses QW).
// =====================================================================
__global__ __launch_bounds__(256, 2) void gptq_gemm_fb(
    const float* __restrict__ X, const int* __restrict__ QW,
    const int* __restrict__ QZ, const float* __restrict__ SC,
    const float* __restrict__ BIAS, float* __restrict__ Y)
{
    constexpr int N = 4096, K = 4096, KB = 512, NT = 64;
    __shared__ __align__(16) u16 Alds[2][128 * 64];
    __shared__ __align__(16) u16 Blds[2][128 * 64];

    const int tid = threadIdx.x, lane = tid & 63, wid = tid >> 6;
    const int m0 = blockIdx.x * 128, n0 = blockIdx.y * 128;

    f32x4 acc[4][4];
#pragma unroll
    for (int i = 0; i < 4; i++)
#pragma unroll
        for (int j = 0; j < 4; j++) acc[i][j] = (f32x4){0.f, 0.f, 0.f, 0.f};

    const int wm = (wid >> 1) * 64, wn = (wid & 1) * 64;
    const int lrowA = tid >> 3;
    const float* gA = X + (u64)(m0 + lrowA) * K + (tid & 7) * 8;
    const int sA = ((tid & 7) ^ (lrowA & 7)) * 8;
    const int nl = tid >> 1, kq0 = (tid & 1) * 4;
    const int nglob = n0 + nl;
    const int* qrow = QW + (u64)nglob * KB;
    const int nl7 = nl & 7, zsh = (nglob & 7) * 4;
    const float* scp = SC + nglob;
    const int* qzp = QZ + (nglob >> 3);
    const int fr = lane & 15, quad = lane >> 4, fr7 = fr & 7;

    float4 af32[8];
    int4 q4;
    float sf;
    int zw;

    auto FETCH = [&](int t) {
        const int kt = t * 64;
#pragma unroll
        for (int i = 0; i < 4; i++) {
            const float* pa = gA + (u64)i * 32 * K + kt;
            af32[2 * i] = *(const float4*)pa;
            af32[2 * i + 1] = *(const float4*)(pa + 4);
        }
        q4 = *(const int4*)(qrow + (kt >> 3) + kq0);
        const int g = t >> 1;
        sf = scp[g * N];
        zw = qzp[g * (N / 8)];
    };
    auto STORE = [&](int buf) {
#pragma unroll
        for (int i = 0; i < 4; i++) {
            const float4 f0 = af32[2 * i], f1 = af32[2 * i + 1];
            uint4 w;
            w.x = cvt_pk(f0.x, f1.x); w.y = cvt_pk(f0.y, f1.y);
            w.z = cvt_pk(f0.z, f1.z); w.w = cvt_pk(f0.w, f1.w);
            *(uint4*)(&Alds[buf][(i * 32 + lrowA) * 64 + sA]) = w;
        }
        const int z = (zw >> zsh) & 0xF;
        const _Float16 hs = (_Float16)sf;
        const _Float16 hz = (_Float16)(float)(1024 + z);
        const f16x2 cs2 = {hs, hs}, cz2 = {hz, hz};
        const int qv[4] = {q4.x, q4.y, q4.z, q4.w};
#pragma unroll
        for (int c = 0; c < 4; c++) {
            const f16x8 wv = unpack_dq((u32)qv[c], cz2, cs2);
            const int gran = ((kq0 + c) ^ nl7) * 8;
            *(f16x8*)(&Blds[buf][nl * 64 + gran]) = wv;
        }
    };
    auto COMPUTE = [&](int buf) {
#pragma unroll
        for (int ks = 0; ks < 2; ks++) {
            const int gsw = ((ks * 4 + quad) ^ fr7) * 8;
            f16x8 af[4], bfr[4];
#pragma unroll
            for (int i = 0; i < 4; i++)
                af[i] = *(const f16x8*)(&Alds[buf][(wm + i * 16 + fr) * 64 + gsw]);
#pragma unroll
            for (int i = 0; i < 4; i++)
                bfr[i] = *(const f16x8*)(&Blds[buf][(wn + i * 16 + fr) * 64 + gsw]);
#pragma unroll
            for (int mi = 0; mi < 4; mi++)
#pragma unroll
                for (int ni = 0; ni < 4; ni++)
                    acc[mi][ni] = __builtin_amdgcn_mfma_f32_16x16x32_f16(
                        af[mi], bfr[ni], acc[mi][ni], 0, 0, 0);
        }
    };

    FETCH(0); STORE(0); __syncthreads();
#pragma unroll 2
    for (int t = 0; t < NT; ++t) {
        const int cur = t & 1;
        if (t + 1 < NT) FETCH(t + 1);
        COMPUTE(cur);
        if (t + 1 < NT) STORE(cur ^ 1);
        __syncthreads();
    }
    const int cn = lane & 15, q4r = quad * 4;
#pragma unroll
    for (int ni = 0; ni < 4; ni++) {
        const int col = n0 + wn + ni * 16 + cn;
        const float bz = BIAS[col];
#pragma unroll
        for (int mi = 0; mi < 4; mi++) {
            const int rbase = m0 + wm + mi * 16 + q4r;
#pragma unroll
            for (int r = 0; r < 4; r++)
                Y[(u64)(rbase + r) * N + col] = acc[mi][ni][r] + bz;
        }
    }
}

extern "C" void kernel_launch(void* const* d_in, const int* in_sizes, int n_in,
                              void* d_out, int out_size, void* d_ws, size_t ws_size,
                              hipStream_t stream) {
    const float* X    = (const float*)d_in[0];   // x       [2,4096,4096] f32
    const int*   QW   = (const int*)d_in[1];     // qweight [4096,512] int32
    const int*   QZ   = (const int*)d_in[2];     // qzeros  [32,512] int32
    const float* SC   = (const float*)d_in[3];   // scales  [32,4096] f32
    const float* BIAS = (const float*)d_in[4];   // bias    [4096] f32
    float* Y = (float*)d_out;                    // [8192,4096] f32

    const size_t needXh = (size_t)8192 * 4096 * sizeof(u16);   // 64 MiB
    const size_t needAll = needXh + (size_t)512 * 4096 * 4;    // + 8 MiB
    if (ws_size >= needAll) {
        u16* Xh  = (u16*)d_ws;
        int* QWt = (int*)((char*)d_ws + needXh);
        gptq_prepass<<<4096, 256, 0, stream>>>(X, Xh);
        gptq_transpose<<<dim3(8, 64), 256, 0, stream>>>(QW, QWt);
        dim3 grid(64, 32, 1);                               // M/128 x N/128
        gptq_gemm_dma<<<grid, 256, 0, stream>>>(Xh, QWt, QZ, SC, BIAS, Y);
    } else {
        dim3 grid(64, 32, 1);                               // M/128 x N/128
        gptq_gemm_fb<<<grid, 256, 0, stream>>>(X, QW, QZ, SC, BIAS, Y);
    }
}

// Round 8
// 480.781 us; speedup vs baseline: 1.1299x; 1.1299x over previous
//
#include <hip/hip_runtime.h>
#include <cstdint>

typedef unsigned short u16;
typedef unsigned int   u32;
typedef unsigned long long u64;

typedef _Float16 f16x2 __attribute__((ext_vector_type(2)));
typedef _Float16 f16x8 __attribute__((ext_vector_type(8)));
typedef float    f32x4 __attribute__((ext_vector_type(4)));

// pack two f32 into fp16x2 bits (RTZ fine: inputs exactly fp16-representable)
__device__ __forceinline__ u32 cvt_pk(float a, float b) {
    return __builtin_bit_cast(u32, __builtin_amdgcn_cvt_pkrtz(a, b));
}

// Unpack one int32 (8 nibbles LSB-first along K) -> dequantized f16x8 in the
// k-order [0,4,1,5,2,6,3,7]. Exact math, verified R1-R7 (absmax 0.0625).
__device__ __forceinline__ f16x8 unpack_dq(u32 q, f16x2 cz, f16x2 cs) {
    const u32 b0 = (q & 0x000F000Fu) | 0x64006400u;         // nib0,nib4
    const u32 b1 = ((q >> 4) & 0x000F000Fu) | 0x64006400u;  // nib1,nib5
    const u32 b2 = ((q >> 8) & 0x000F000Fu) | 0x64006400u;  // nib2,nib6
    const u32 b3 = ((q >> 12) & 0x000F000Fu) | 0x64006400u; // nib3,nib7
    const f16x2 w0 = (__builtin_bit_cast(f16x2, b0) - cz) * cs;
    const f16x2 w1 = (__builtin_bit_cast(f16x2, b1) - cz) * cs;
    const f16x2 w2 = (__builtin_bit_cast(f16x2, b2) - cz) * cs;
    const f16x2 w3 = (__builtin_bit_cast(f16x2, b3) - cz) * cs;
    uint4 w;
    w.x = __builtin_bit_cast(u32, w0);
    w.y = __builtin_bit_cast(u32, w1);
    w.z = __builtin_bit_cast(u32, w2);
    w.w = __builtin_bit_cast(u32, w3);
    return __builtin_bit_cast(f16x8, w);
}

__device__ __forceinline__ void load_lds16(const void* g, void* l) {
    __builtin_amdgcn_global_load_lds(
        (const __attribute__((address_space(1))) void*)g,
        (__attribute__((address_space(3))) void*)l,
        16, 0, 0);
}

// =====================================================================
// Prepass A: X f32 [8192,4096] -> Xh f16, tiled LDS-image layout.
// (unchanged) u16 off = r*64 + sg*8, sg = g ^ (r&7), granule g holds
// k-local [8g,8g+8) in order [0,4,1,5,2,6,3,7].
// =====================================================================
__global__ __launch_bounds__(256) void gptq_prepass(
    const float* __restrict__ X, u16* __restrict__ Xh)
{
    const u32 tile = blockIdx.x;          // 0..4095 : mt = tile>>6, t = tile&63
    const u32 mt = tile >> 6, t = tile & 63;
    const float* bsrc = X + ((u64)mt << 19) + t * 64;
    u16* bdst = Xh + ((u64)tile << 13);
#pragma unroll
    for (int pass = 0; pass < 4; ++pass) {
        const u32 idx = pass * 256 + threadIdx.x;       // 0..1023
        const u32 r = idx >> 3, sg = idx & 7, g = sg ^ (r & 7);
        const float* s = bsrc + ((u64)r << 12) + g * 8;
        const float4 f0 = *(const float4*)s;
        const float4 f1 = *(const float4*)(s + 4);
        uint4 w;
        w.x = cvt_pk(f0.x, f1.x);
        w.y = cvt_pk(f0.y, f1.y);
        w.z = cvt_pk(f0.z, f1.z);
        w.w = cvt_pk(f0.w, f1.w);
        *(uint4*)(bdst + idx * 8) = w;
    }
}

// =====================================================================
// Prepass B (new): QW [4096,512] -> Bt, fully dequantized f16 in MFMA
// fragment layout. Bt[t:64][ks:2][n16:256][lane:64][j:8] f16 (32 MB):
//   chunk = t*8 + ks*4 + quad covers k [8c,8c+8) in order [0,4,1,5,2,6,3,7]
//   lane slot = quad*16 + (n&15).
// GEMM reads one f16x8 fragment as a single b128; a wave's 64 lanes read
// one contiguous 1 KB run. Dequant math identical to unpack_dq -> values
// bit-identical to the in-loop path.
// =====================================================================
__global__ __launch_bounds__(256) void gptq_dequantB(
    const int* __restrict__ QW, const int* __restrict__ QZ,
    const float* __restrict__ SC, u16* __restrict__ Bt)
{
    __shared__ int tile[64][65];
    const u32 bkq = blockIdx.x;           // 0..7   (64 chunks each)
    const u32 bn  = blockIdx.y;           // 0..63  (64 cols each)
    const u32 t = threadIdx.x;
    const u32 r = t >> 4, c4 = (t & 15) * 4;
    // load + transpose QW 64x64 block (coalesced along k)
#pragma unroll
    for (int p = 0; p < 4; ++p) {
        const u32 row = p * 16 + r;       // n-local
        const int4 v = *(const int4*)(QW + (u64)(bn * 64 + row) * 512
                                         + bkq * 64 + c4);
        tile[row][c4 + 0] = v.x; tile[row][c4 + 1] = v.y;
        tile[row][c4 + 2] = v.z; tile[row][c4 + 3] = v.w;
    }
    __syncthreads();
    char* BtB = (char*)Bt;
#pragma unroll
    for (int p = 0; p < 4; ++p) {
        const u32 kql = p * 16 + r;
        const u32 chunk = bkq * 64 + kql;           // 0..511
        const u32 g = chunk >> 4;                   // group (k/128)
        const u32 quad = chunk & 3;
        const u64 base = ((u64)((chunk >> 2) * 256)) * 1024 + quad * 256;
#pragma unroll
        for (int e = 0; e < 4; ++e) {
            const u32 n = bn * 64 + c4 + e;
            const u32 q = (u32)tile[c4 + e][kql];
            const float s = SC[g * 4096 + n];
            const int zw = QZ[g * 512 + (n >> 3)];
            const int z = (zw >> ((n & 7) * 4)) & 0xF;
            const _Float16 hs = (_Float16)s;
            const _Float16 hz = (_Float16)(float)(1024 + z);
            const f16x8 v = unpack_dq(q, (f16x2){hz, hz}, (f16x2){hs, hs});
            *(f16x8*)(BtB + base + (u64)(n >> 4) * 1024 + (n & 15) * 16) = v;
        }
    }
}

// =====================================================================
// Main GEMM (new): A via global_load_lds DMA (R6 machinery, counted
// vmcnt), B fragments loaded DIRECTLY from pre-dequantized Bt -- zero
// dequant VALU in the hot loop. Block 128x256, 4 waves of 128x64.
// =====================================================================
__global__ __launch_bounds__(256, 2) void gptq_gemm_dq(
    const u16* __restrict__ Xh,     // [M/128][K/64][128][64] f16, swizzled
    const u16* __restrict__ Bt,     // fragment-layout f16 B (32 MB)
    const float* __restrict__ BIAS, // [N] f32
    float* __restrict__ Y)          // [M, N] f32
{
    constexpr int N = 4096, NT = 64;

    __shared__ __align__(16) u16 Alds[2][128 * 64];   // 2 x 16 KB, A only

    const int tid  = threadIdx.x;
    const int lane = tid & 63;
    const int wid  = tid >> 6;

    const int mt = blockIdx.x;       // 0..63
    const int m0 = mt * 128;
    const int n0 = blockIdx.y * 256; // gridDim.y = 16

    f32x4 acc[8][4];
#pragma unroll
    for (int i = 0; i < 8; i++)
#pragma unroll
        for (int j = 0; j < 4; j++)
            acc[i][j] = (f32x4){0.f, 0.f, 0.f, 0.f};

    const int fr   = lane & 15;
    const int quad = lane >> 4;
    const int fr7  = fr & 7;

    // A staging: per-lane global source (layout == LDS image), linear LDS dest
    const char* xsrc = (const char*)Xh + (((u64)mt * NT) << 14)
                     + wid * 4096 + lane * 16;

    // B fragments: byte = ((t*2+ks)<<18) + (nb16+ni)*1024 + lane*16
    const int nb16 = (n0 >> 4) + wid * 4;
    const char* btb = (const char*)Bt + (u64)nb16 * 1024 + lane * 16;

    f16x8 bq[2][2][4];        // [nb][ks][ni], static indices only

    auto STAGE = [&](int buf, int t) {                  // 4 DMA loads
        const char* s = xsrc + ((u64)t << 14);
        char* d = (char*)&Alds[buf][0] + wid * 4096;
#pragma unroll
        for (int i = 0; i < 4; i++)
            load_lds16(s + i * 1024, d + i * 1024);
    };

    auto FETCH_B = [&](int t, int nb) {                 // 8 coalesced b128
#pragma unroll
        for (int ks = 0; ks < 2; ks++) {
            const char* p = btb + ((u64)(t * 2 + ks) << 18);
#pragma unroll
            for (int ni = 0; ni < 4; ni++)
                bq[nb][ks][ni] = *(const f16x8*)(p + ni * 1024);
        }
    };

    auto COMPUTE = [&](int buf, int nb) {
#pragma unroll
        for (int ks = 0; ks < 2; ks++) {
            const int gsw = ((ks * 4 + quad) ^ fr7) * 8;
            __builtin_amdgcn_s_setprio(1);
#pragma unroll
            for (int mi = 0; mi < 8; mi++) {
                const f16x8 af =
                    *(const f16x8*)(&Alds[buf][(mi * 16 + fr) * 64 + gsw]);
#pragma unroll
                for (int ni = 0; ni < 4; ni++)
                    acc[mi][ni] = __builtin_amdgcn_mfma_f32_16x16x32_f16(
                        af, bq[nb][ks][ni], acc[mi][ni], 0, 0, 0);
            }
            __builtin_amdgcn_s_setprio(0);
        }
    };

    // ---- prologue: B(0):8, STAGE(0):4, STAGE(1):4 ----
    FETCH_B(0, 0);
    STAGE(0, 0);
    STAGE(1, 1);
    // STAGE(1) may stay in flight; tile 0 + B(0) guaranteed via compiler/vmcnt
    asm volatile("s_waitcnt vmcnt(4)\n\ts_barrier" ::: "memory");

    // ---- main loop: 31 pairs, counted vmcnt, no drain-to-0 ----
    for (int t = 0; t <= 60; t += 2) {
        // even: compute tile t (buf0/nb0)
        FETCH_B(t + 1, 1);               // 8
        COMPUTE(0, 0);
        asm volatile("s_barrier" ::: "memory");          // buf0 free
        STAGE(0, t + 2);                 // 4 DMA
        // ensure STAGE(t+1) landed; newer = B8 + STAGE4 = 12
        asm volatile("s_waitcnt vmcnt(12)\n\ts_barrier" ::: "memory");

        // odd: compute tile t+1 (buf1/nb1)
        FETCH_B(t + 2, 0);               // 8
        COMPUTE(1, 1);
        asm volatile("s_barrier" ::: "memory");          // buf1 free
        STAGE(1, t + 3);                 // 4 DMA
        // ensure STAGE(t+2) landed; newer = B8 + STAGE4 = 12
        asm volatile("s_waitcnt vmcnt(12)\n\ts_barrier" ::: "memory");
    }

    // ---- tail: tiles 62, 63 (already staged) ----
    FETCH_B(63, 1);                      // 8
    COMPUTE(0, 0);                       // tile 62
    // ensure STAGE(63) landed; newer = B(63):8
    asm volatile("s_waitcnt vmcnt(8)\n\ts_barrier" ::: "memory");
    COMPUTE(1, 1);                       // tile 63

    // ---- epilogue: + bias. C/D map: col=lane&15, row=quad*4+reg ----
    const int cn  = lane & 15;
    const int q4r = quad * 4;
#pragma unroll
    for (int ni = 0; ni < 4; ni++) {
        const int col = n0 + wid * 64 + ni * 16 + cn;
        const float bz = BIAS[col];
#pragma unroll
        for (int mi = 0; mi < 8; mi++) {
            const int rbase = m0 + mi * 16 + q4r;
#pragma unroll
            for (int r = 0; r < 4; r++) {
                Y[(u64)(rbase + r) * N + col] = acc[mi][ni][r] + bz;
            }
        }
    }
}

// =====================================================================
// Mid path (ws in [72,96) MB): exact R6 winner -- transpose + in-loop
// dequant GEMM (measured 273us).
// =====================================================================
__global__ __launch_bounds__(256) void gptq_transpose(
    const int* __restrict__ QW, int* __restrict__ QWt)
{
    __shared__ int tile[64][65];
    const u32 bkq = blockIdx.x, bn = blockIdx.y;
    const u32 t = threadIdx.x;
    const u32 r = t >> 4, c4 = (t & 15) * 4;
#pragma unroll
    for (int p = 0; p < 4; ++p) {
        const u32 row = p * 16 + r;
        const int4 v = *(const int4*)(QW + (u64)(bn * 64 + row) * 512
                                         + bkq * 64 + c4);
        tile[row][c4 + 0] = v.x; tile[row][c4 + 1] = v.y;
        tile[row][c4 + 2] = v.z; tile[row][c4 + 3] = v.w;
    }
    __syncthreads();
#pragma unroll
    for (int p = 0; p < 4; ++p) {
        const u32 kql = p * 16 + r;
        int4 v;
        v.x = tile[c4 + 0][kql]; v.y = tile[c4 + 1][kql];
        v.z = tile[c4 + 2][kql]; v.w = tile[c4 + 3][kql];
        *(int4*)(QWt + (u64)(bkq * 64 + kql) * 4096 + bn * 64 + c4) = v;
    }
}

__global__ __launch_bounds__(256, 2) void gptq_gemm_dma(
    const u16* __restrict__ Xh, const int* __restrict__ QWt,
    const int* __restrict__ QZ, const float* __restrict__ SC,
    const float* __restrict__ BIAS, float* __restrict__ Y)
{
    constexpr int N = 4096, NT = 64;
    __shared__ __align__(16) u16 Alds[2][128 * 64];
    const int tid = threadIdx.x, lane = tid & 63, wid = tid >> 6;
    const int mt = blockIdx.x, m0 = mt * 128, n0 = blockIdx.y * 256;
    f32x4 acc[8][4];
#pragma unroll
    for (int i = 0; i < 8; i++)
#pragma unroll
        for (int j = 0; j < 4; j++) acc[i][j] = (f32x4){0.f, 0.f, 0.f, 0.f};
    const int fr = lane & 15, quad = lane >> 4, fr7 = fr & 7;
    const char* xsrc = (const char*)Xh + (((u64)mt * NT) << 14)
                     + wid * 4096 + lane * 16;
    const int nbase = n0 + wid * 64 + fr;
    const char* QWtB = (const char*)QWt;
    const u64 qtbase = (u64)((u32)(quad * 4096 + nbase) * 4u);
    int bq[2][8];
    float sf_st[4];
    int zw_st[4];
    f16x2 cs[4], cz[4];
    const int zsh = fr7 * 4;
    auto STAGE = [&](int buf, int t) {
        const char* s = xsrc + ((u64)t << 14);
        char* d = (char*)&Alds[buf][0] + wid * 4096;
#pragma unroll
        for (int i = 0; i < 4; i++) load_lds16(s + i * 1024, d + i * 1024);
    };
    auto FETCH_B = [&](int t, int nb) {
        const char* p = QWtB + ((u64)t << 17) + qtbase;
#pragma unroll
        for (int ni = 0; ni < 4; ni++) {
            bq[nb][ni * 2 + 0] = *(const int*)(p + ni * 64);
            bq[nb][ni * 2 + 1] = *(const int*)(p + 65536 + ni * 64);
        }
    };
    auto FETCH_SZ = [&](int g) {
#pragma unroll
        for (int ni = 0; ni < 4; ni++) {
            sf_st[ni] = SC[g * N + nbase + ni * 16];
            zw_st[ni] = QZ[g * (N / 8) + ((nbase + ni * 16) >> 3)];
        }
    };
    auto CONV_SZ = [&]() {
#pragma unroll
        for (int ni = 0; ni < 4; ni++) {
            const int z = (zw_st[ni] >> zsh) & 0xF;
            const _Float16 hs = (_Float16)sf_st[ni];
            const _Float16 hz = (_Float16)(float)(1024 + z);
            cs[ni] = (f16x2){hs, hs};
            cz[ni] = (f16x2){hz, hz};
        }
    };
    auto COMPUTE = [&](int buf, int nb) {
#pragma unroll
        for (int ks = 0; ks < 2; ks++) {
            f16x8 bfr[4];
#pragma unroll
            for (int ni = 0; ni < 4; ni++)
                bfr[ni] = unpack_dq((u32)bq[nb][ni * 2 + ks], cz[ni], cs[ni]);
            const int gsw = ((ks * 4 + quad) ^ fr7) * 8;
            __builtin_amdgcn_s_setprio(1);
#pragma unroll
            for (int mi = 0; mi < 8; mi++) {
                const f16x8 af =
                    *(const f16x8*)(&Alds[buf][(mi * 16 + fr) * 64 + gsw]);
#pragma unroll
                for (int ni = 0; ni < 4; ni++)
                    acc[mi][ni] = __builtin_amdgcn_mfma_f32_16x16x32_f16(
                        af, bfr[ni], acc[mi][ni], 0, 0, 0);
            }
            __builtin_amdgcn_s_setprio(0);
        }
    };
    FETCH_B(0, 0);
    FETCH_SZ(0);
    STAGE(0, 0);
    STAGE(1, 1);
    CONV_SZ();
    asm volatile("s_waitcnt vmcnt(4)\n\ts_barrier" ::: "memory");
    for (int t = 0; t <= 60; t += 2) {
        FETCH_B(t + 1, 1);
        FETCH_SZ((t >> 1) + 1);
        COMPUTE(0, 0);
        asm volatile("s_barrier" ::: "memory");
        STAGE(0, t + 2);
        asm volatile("s_waitcnt vmcnt(20)\n\ts_barrier" ::: "memory");
        FETCH_B(t + 2, 0);
        COMPUTE(1, 1);
        CONV_SZ();
        asm volatile("s_barrier" ::: "memory");
        STAGE(1, t + 3);
        asm volatile("s_waitcnt vmcnt(12)\n\ts_barrier" ::: "memory");
    }
    FETCH_B(63, 1);
    COMPUTE(0, 0);
    asm volatile("s_waitcnt vmcnt(8)\n\ts_barrier" ::: "memory");
    COMPUTE(1, 1);
    const int cn = lane & 15, q4r = quad * 4;
#pragma unroll
    for (int ni = 0; ni < 4; ni++) {
        const int col = n0 + wid * 64 + ni * 16 + cn;
        const float bz = BIAS[col];
#pragma unroll
        for (int mi = 0; mi < 8; mi++) {
            const int rbase = m0 + mi * 16 + q4r;
#pragma unroll
            for (int r = 0; r < 4; r++)
                Y[(u64)(rbase + r) * N + col] = acc[mi][ni][r] + bz;
        }
    }
}

// =====================================================================
// Fallback (no ws): R1's verified kernel, unchanged (original inputs).
// =====================================================================
__global__ __launch_bounds__(256, 2) void gptq_gemm_fb(
    const float* __restrict__ X, const int* __restrict__ QW,
    const int* __restrict__ QZ, const float* __restrict__ SC,
    const float* __restrict__ BIAS, float* __restrict__ Y)
{
    constexpr int N = 4096, K = 4096, KB = 512, NT = 64;
    __shared__ __align__(16) u16 Alds[2][128 * 64];
    __shared__ __align__(16) u16 Blds[2][128 * 64];
    const int tid = threadIdx.x, lane = tid & 63, wid = tid >> 6;
    const int m0 = blockIdx.x * 128, n0 = blockIdx.y * 128;
    f32x4 acc[4][4];
#pragma unroll
    for (int i = 0; i < 4; i++)
#pragma unroll
        for (int j = 0; j < 4; j++) acc[i][j] = (f32x4){0.f, 0.f, 0.f, 0.f};
    const int wm = (wid >> 1) * 64, wn = (wid & 1) * 64;
    const int lrowA = tid >> 3;
    const float* gA = X + (u64)(m0 + lrowA) * K + (tid & 7) * 8;
    const int sA = ((tid & 7) ^ (lrowA & 7)) * 8;
    const int nl = tid >> 1, kq0 = (tid & 1) * 4;
    const int nglob = n0 + nl;
    const int* qrow = QW + (u64)nglob * KB;
    const int nl7 = nl & 7, zsh = (nglob & 7) * 4;
    const float* scp = SC + nglob;
    const int* qzp = QZ + (nglob >> 3);
    const int fr = lane & 15, quad = lane >> 4, fr7 = fr & 7;
    float4 af32[8];
    int4 q4;
    float sf;
    int zw;
    auto FETCH = [&](int t) {
        const int kt = t * 64;
#pragma unroll
        for (int i = 0; i < 4; i++) {
            const float* pa = gA + (u64)i * 32 * K + kt;
            af32[2 * i] = *(const float4*)pa;
            af32[2 * i + 1] = *(const float4*)(pa + 4);
        }
        q4 = *(const int4*)(qrow + (kt >> 3) + kq0);
        const int g = t >> 1;
        sf = scp[g * N];
        zw = qzp[g * (N / 8)];
    };
    auto STORE = [&](int buf) {
#pragma unroll
        for (int i = 0; i < 4; i++) {
            const float4 f0 = af32[2 * i], f1 = af32[2 * i + 1];
            uint4 w;
            w.x = cvt_pk(f0.x, f1.x); w.y = cvt_pk(f0.y, f1.y);
            w.z = cvt_pk(f0.z, f1.z); w.w = cvt_pk(f0.w, f1.w);
            *(uint4*)(&Alds[buf][(i * 32 + lrowA) * 64 + sA]) = w;
        }
        const int z = (zw >> zsh) & 0xF;
        const _Float16 hs = (_Float16)sf;
        const _Float16 hz = (_Float16)(float)(1024 + z);
        const f16x2 cs2 = {hs, hs}, cz2 = {hz, hz};
        const int qv[4] = {q4.x, q4.y, q4.z, q4.w};
#pragma unroll
        for (int c = 0; c < 4; c++) {
            const f16x8 wv = unpack_dq((u32)qv[c], cz2, cs2);
            const int gran = ((kq0 + c) ^ nl7) * 8;
            *(f16x8*)(&Blds[buf][nl * 64 + gran]) = wv;
        }
    };
    auto COMPUTE = [&](int buf) {
#pragma unroll
        for (int ks = 0; ks < 2; ks++) {
            const int gsw = ((ks * 4 + quad) ^ fr7) * 8;
            f16x8 af[4], bfr[4];
#pragma unroll
            for (int i = 0; i < 4; i++)
                af[i] = *(const f16x8*)(&Alds[buf][(wm + i * 16 + fr) * 64 + gsw]);
#pragma unroll
            for (int i = 0; i < 4; i++)
                bfr[i] = *(const f16x8*)(&Blds[buf][(wn + i * 16 + fr) * 64 + gsw]);
#pragma unroll
            for (int mi = 0; mi < 4; mi++)
#pragma unroll
                for (int ni = 0; ni < 4; ni++)
                    acc[mi][ni] = __builtin_amdgcn_mfma_f32_16x16x32_f16(
                        af[mi], bfr[ni], acc[mi][ni], 0, 0, 0);
        }
    };
    FETCH(0); STORE(0); __syncthreads();
#pragma unroll 2
    for (int t = 0; t < NT; ++t) {
        const int cur = t & 1;
        if (t + 1 < NT) FETCH(t + 1);
        COMPUTE(cur);
        if (t + 1 < NT) STORE(cur ^ 1);
        __syncthreads();
    }
    const int cn = lane & 15, q4r = quad * 4;
#pragma unroll
    for (int ni = 0; ni < 4; ni++) {
        const int col = n0 + wn + ni * 16 + cn;
        const float bz = BIAS[col];
#pragma unroll
        for (int mi = 0; mi < 4; mi++) {
            const int rbase = m0 + wm + mi * 16 + q4r;
#pragma unroll
            for (int r = 0; r < 4; r++)
                Y[(u64)(rbase + r) * N + col] = acc[mi][ni][r] + bz;
        }
    }
}

extern "C" void kernel_launch(void* const* d_in, const int* in_sizes, int n_in,
                              void* d_out, int out_size, void* d_ws, size_t ws_size,
                              hipStream_t stream) {
    const float* X    = (const float*)d_in[0];   // x       [2,4096,4096] f32
    const int*   QW   = (const int*)d_in[1];     // qweight [4096,512] int32
    const int*   QZ   = (const int*)d_in[2];     // qzeros  [32,512] int32
    const float* SC   = (const float*)d_in[3];   // scales  [32,4096] f32
    const float* BIAS = (const float*)d_in[4];   // bias    [4096] f32
    float* Y = (float*)d_out;                    // [8192,4096] f32

    const size_t needXh = (size_t)8192 * 4096 * sizeof(u16);       // 64 MiB
    const size_t needNew = needXh + (size_t)4096 * 4096 * 2;       // + 32 MiB
    const size_t needMid = needXh + (size_t)512 * 4096 * 4;        // + 8 MiB
    if (ws_size >= needNew) {
        u16* Xh = (u16*)d_ws;
        u16* Bt = (u16*)((char*)d_ws + needXh);
        gptq_prepass<<<4096, 256, 0, stream>>>(X, Xh);
        gptq_dequantB<<<dim3(8, 64), 256, 0, stream>>>(QW, QZ, SC, Bt);
        dim3 grid(64, 16, 1);                               // M/128 x N/256
        gptq_gemm_dq<<<grid, 256, 0, stream>>>(Xh, Bt, BIAS, Y);
    } else if (ws_size >= needMid) {
        u16* Xh  = (u16*)d_ws;
        int* QWt = (int*)((char*)d_ws + needXh);
        gptq_prepass<<<4096, 256, 0, stream>>>(X, Xh);
        gptq_transpose<<<dim3(8, 64), 256, 0, stream>>>(QW, QWt);
        dim3 grid(64, 16, 1);                               // M/128 x N/256
        gptq_gemm_dma<<<grid, 256, 0, stream>>>(Xh, QWt, QZ, SC, BIAS, Y);
    } else {
        dim3 grid(64, 32, 1);                               // M/128 x N/128
        gptq_gemm_fb<<<grid, 256, 0, stream>>>(X, QW, QZ, SC, BIAS, Y);
    }
}

// Round 9
// 479.444 us; speedup vs baseline: 1.1331x; 1.0028x over previous
//
#include <hip/hip_runtime.h>
#include <cstdint>

typedef unsigned short u16;
typedef unsigned int   u32;
typedef unsigned long long u64;

typedef _Float16 f16x2 __attribute__((ext_vector_type(2)));
typedef _Float16 f16x8 __attribute__((ext_vector_type(8)));
typedef float    f32x4 __attribute__((ext_vector_type(4)));

// pack two f32 into fp16x2 bits (RTZ fine: inputs exactly fp16-representable)
__device__ __forceinline__ u32 cvt_pk(float a, float b) {
    return __builtin_bit_cast(u32, __builtin_amdgcn_cvt_pkrtz(a, b));
}

// Unpack one int32 (8 nibbles LSB-first along K) -> dequantized f16x8 in the
// k-order [0,4,1,5,2,6,3,7]. Exact math, verified R1-R8 (absmax 0.0625).
__device__ __forceinline__ f16x8 unpack_dq(u32 q, f16x2 cz, f16x2 cs) {
    const u32 b0 = (q & 0x000F000Fu) | 0x64006400u;         // nib0,nib4
    const u32 b1 = ((q >> 4) & 0x000F000Fu) | 0x64006400u;  // nib1,nib5
    const u32 b2 = ((q >> 8) & 0x000F000Fu) | 0x64006400u;  // nib2,nib6
    const u32 b3 = ((q >> 12) & 0x000F000Fu) | 0x64006400u; // nib3,nib7
    const f16x2 w0 = (__builtin_bit_cast(f16x2, b0) - cz) * cs;
    const f16x2 w1 = (__builtin_bit_cast(f16x2, b1) - cz) * cs;
    const f16x2 w2 = (__builtin_bit_cast(f16x2, b2) - cz) * cs;
    const f16x2 w3 = (__builtin_bit_cast(f16x2, b3) - cz) * cs;
    uint4 w;
    w.x = __builtin_bit_cast(u32, w0);
    w.y = __builtin_bit_cast(u32, w1);
    w.z = __builtin_bit_cast(u32, w2);
    w.w = __builtin_bit_cast(u32, w3);
    return __builtin_bit_cast(f16x8, w);
}

__device__ __forceinline__ void load_lds16(const void* g, void* l) {
    __builtin_amdgcn_global_load_lds(
        (const __attribute__((address_space(1))) void*)g,
        (__attribute__((address_space(3))) void*)l,
        16, 0, 0);
}

// =====================================================================
// Prepass A: X f32 [8192,4096] -> Xh f16, tiled LDS-image layout.
// (unchanged) u16 off = r*64 + sg*8, sg = g ^ (r&7), granule g holds
// k-local [8g,8g+8) in order [0,4,1,5,2,6,3,7].
// =====================================================================
__global__ __launch_bounds__(256) void gptq_prepass(
    const float* __restrict__ X, u16* __restrict__ Xh)
{
    const u32 tile = blockIdx.x;          // 0..4095 : mt = tile>>6, t = tile&63
    const u32 mt = tile >> 6, t = tile & 63;
    const float* bsrc = X + ((u64)mt << 19) + t * 64;
    u16* bdst = Xh + ((u64)tile << 13);
#pragma unroll
    for (int pass = 0; pass < 4; ++pass) {
        const u32 idx = pass * 256 + threadIdx.x;       // 0..1023
        const u32 r = idx >> 3, sg = idx & 7, g = sg ^ (r & 7);
        const float* s = bsrc + ((u64)r << 12) + g * 8;
        const float4 f0 = *(const float4*)s;
        const float4 f1 = *(const float4*)(s + 4);
        uint4 w;
        w.x = cvt_pk(f0.x, f1.x);
        w.y = cvt_pk(f0.y, f1.y);
        w.z = cvt_pk(f0.z, f1.z);
        w.w = cvt_pk(f0.w, f1.w);
        *(uint4*)(bdst + idx * 8) = w;
    }
}

// =====================================================================
// Prepass B: QW -> Bt, fully dequantized f16 in MFMA fragment layout.
// (unchanged from R8, measured win) Bt[(chunk>>2)*256 + n16][quad*16+n15][8]
// =====================================================================
__global__ __launch_bounds__(256) void gptq_dequantB(
    const int* __restrict__ QW, const int* __restrict__ QZ,
    const float* __restrict__ SC, u16* __restrict__ Bt)
{
    __shared__ int tile[64][65];
    const u32 bkq = blockIdx.x;           // 0..7   (64 chunks each)
    const u32 bn  = blockIdx.y;           // 0..63  (64 cols each)
    const u32 t = threadIdx.x;
    const u32 r = t >> 4, c4 = (t & 15) * 4;
#pragma unroll
    for (int p = 0; p < 4; ++p) {
        const u32 row = p * 16 + r;       // n-local
        const int4 v = *(const int4*)(QW + (u64)(bn * 64 + row) * 512
                                         + bkq * 64 + c4);
        tile[row][c4 + 0] = v.x; tile[row][c4 + 1] = v.y;
        tile[row][c4 + 2] = v.z; tile[row][c4 + 3] = v.w;
    }
    __syncthreads();
    char* BtB = (char*)Bt;
#pragma unroll
    for (int p = 0; p < 4; ++p) {
        const u32 kql = p * 16 + r;
        const u32 chunk = bkq * 64 + kql;           // 0..511
        const u32 g = chunk >> 4;                   // group (k/128)
        const u32 quad = chunk & 3;
        const u64 base = ((u64)((chunk >> 2) * 256)) * 1024 + quad * 256;
#pragma unroll
        for (int e = 0; e < 4; ++e) {
            const u32 n = bn * 64 + c4 + e;
            const u32 q = (u32)tile[c4 + e][kql];
            const float s = SC[g * 4096 + n];
            const int zw = QZ[g * 512 + (n >> 3)];
            const int z = (zw >> ((n & 7) * 4)) & 0xF;
            const _Float16 hs = (_Float16)s;
            const _Float16 hz = (_Float16)(float)(1024 + z);
            const f16x8 v = unpack_dq(q, (f16x2){hz, hz}, (f16x2){hs, hs});
            *(f16x8*)(BtB + base + (u64)(n >> 4) * 1024 + (n & 15) * 16) = v;
        }
    }
}

// =====================================================================
// Main GEMM: R8's zero-dequant kernel deepened to a 4-buffer A pipeline
// (3 tiles in flight). Per phase: {COMPUTE(t) | B(t+2) -> STAGE(t+3) ->
// vmcnt(24)+barrier}. Issue order pinned with sched_barrier so the
// in-order vmem queue counts are exact; B issued BEFORE the STAGEs that
// must stay in flight, so the compiler's B-register wait doesn't drain
// the deep prefetch. Tail handled by wrap-around staging (&63) into
// buffers never read again -> uniform counts, no special-case tail.
// =====================================================================
__global__ __launch_bounds__(256, 2) void gptq_gemm_dq(
    const u16* __restrict__ Xh,     // [M/128][K/64][128][64] f16, swizzled
    const u16* __restrict__ Bt,     // fragment-layout f16 B (32 MB)
    const float* __restrict__ BIAS, // [N] f32
    float* __restrict__ Y)          // [M, N] f32
{
    constexpr int N = 4096, NT = 64;

    __shared__ __align__(16) u16 Alds[4][128 * 64];   // 4 x 16 KB

    const int tid  = threadIdx.x;
    const int lane = tid & 63;
    const int wid  = tid >> 6;

    const int mt = blockIdx.x;       // 0..63
    const int m0 = mt * 128;
    const int n0 = blockIdx.y * 256; // gridDim.y = 16

    f32x4 acc[8][4];
#pragma unroll
    for (int i = 0; i < 8; i++)
#pragma unroll
        for (int j = 0; j < 4; j++)
            acc[i][j] = (f32x4){0.f, 0.f, 0.f, 0.f};

    const int fr   = lane & 15;
    const int quad = lane >> 4;
    const int fr7  = fr & 7;

    // A staging: per-lane global source (layout == LDS image), linear LDS dest
    const char* xsrc = (const char*)Xh + (((u64)mt * NT) << 14)
                     + wid * 4096 + lane * 16;

    // B fragments: byte = ((t*2+ks)<<18) + (nb16+ni)*1024 + lane*16
    const int nb16 = (n0 >> 4) + wid * 4;
    const char* btb = (const char*)Bt + (u64)nb16 * 1024 + lane * 16;

    f16x8 bq[2][2][4];        // [slot][ks][ni], static indices only

    auto STAGE = [&](int buf, int t) {                  // 4 DMA loads
        const char* s = xsrc + ((u64)t << 14);
        char* d = (char*)&Alds[buf][0] + wid * 4096;
#pragma unroll
        for (int i = 0; i < 4; i++)
            load_lds16(s + i * 1024, d + i * 1024);
    };

    auto FETCH_B = [&](int t, int nb) {                 // 8 coalesced b128
#pragma unroll
        for (int ks = 0; ks < 2; ks++) {
            const char* p = btb + ((u64)(t * 2 + ks) << 18);
#pragma unroll
            for (int ni = 0; ni < 4; ni++)
                bq[nb][ks][ni] = *(const f16x8*)(p + ni * 1024);
        }
    };

    auto COMPUTE = [&](int buf, int nb) {
#pragma unroll
        for (int ks = 0; ks < 2; ks++) {
            const int gsw = ((ks * 4 + quad) ^ fr7) * 8;
            __builtin_amdgcn_s_setprio(1);
#pragma unroll
            for (int mi = 0; mi < 8; mi++) {
                const f16x8 af =
                    *(const f16x8*)(&Alds[buf][(mi * 16 + fr) * 64 + gsw]);
#pragma unroll
                for (int ni = 0; ni < 4; ni++)
                    acc[mi][ni] = __builtin_amdgcn_mfma_f32_16x16x32_f16(
                        af, bq[nb][ks][ni], acc[mi][ni], 0, 0, 0);
            }
            __builtin_amdgcn_s_setprio(0);
        }
    };

    // ---- prologue: B(0),B(1) first (so B-waits never force late STAGEs),
    //      then STAGE(0,1,2). vmcnt(8): S0 landed, S1+S2 in flight. ----
    FETCH_B(0, 0);
    FETCH_B(1, 1);
    __builtin_amdgcn_sched_barrier(0);
    STAGE(0, 0);
    STAGE(1, 1);
    STAGE(2, 2);
    __builtin_amdgcn_sched_barrier(0);
    asm volatile("s_waitcnt vmcnt(8)\n\ts_barrier" ::: "memory");

    // ---- peeled phases 0..3 (queue fill: vmcnt 16, then 24 steady) ----
    COMPUTE(0, 0);
    FETCH_B(2, 0);
    __builtin_amdgcn_sched_barrier(0);
    STAGE(3, 3);
    __builtin_amdgcn_sched_barrier(0);
    asm volatile("s_waitcnt vmcnt(16)\n\ts_barrier" ::: "memory");

    COMPUTE(1, 1);
    FETCH_B(3, 1);
    __builtin_amdgcn_sched_barrier(0);
    STAGE(0, 4);
    __builtin_amdgcn_sched_barrier(0);
    asm volatile("s_waitcnt vmcnt(24)\n\ts_barrier" ::: "memory");

    COMPUTE(2, 0);
    FETCH_B(4, 0);
    __builtin_amdgcn_sched_barrier(0);
    STAGE(1, 5);
    __builtin_amdgcn_sched_barrier(0);
    asm volatile("s_waitcnt vmcnt(24)\n\ts_barrier" ::: "memory");

    COMPUTE(3, 1);
    FETCH_B(5, 1);
    __builtin_amdgcn_sched_barrier(0);
    STAGE(2, 6);
    __builtin_amdgcn_sched_barrier(0);
    asm volatile("s_waitcnt vmcnt(24)\n\ts_barrier" ::: "memory");

    // ---- main loop: phases t = 4..63, uniform vmcnt(24) ----
    for (int tb = 1; tb < 16; ++tb) {
        const int t0 = tb * 4;
#pragma unroll
        for (int p = 0; p < 4; ++p) {
            const int t = t0 + p;                 // buf = p, slot = p&1
            COMPUTE(p, p & 1);
            FETCH_B((t + 2) & 63, p & 1);         // wrap: harmless dead loads
            __builtin_amdgcn_sched_barrier(0);
            STAGE((p + 3) & 3, (t + 3) & 63);     // wrap: buffer never re-read
            __builtin_amdgcn_sched_barrier(0);
            asm volatile("s_waitcnt vmcnt(24)\n\ts_barrier" ::: "memory");
        }
    }

    // ---- epilogue: + bias. C/D map: col=lane&15, row=quad*4+reg ----
    const int cn  = lane & 15;
    const int q4r = quad * 4;
#pragma unroll
    for (int ni = 0; ni < 4; ni++) {
        const int col = n0 + wid * 64 + ni * 16 + cn;
        const float bz = BIAS[col];
#pragma unroll
        for (int mi = 0; mi < 8; mi++) {
            const int rbase = m0 + mi * 16 + q4r;
#pragma unroll
            for (int r = 0; r < 4; r++) {
                Y[(u64)(rbase + r) * N + col] = acc[mi][ni][r] + bz;
            }
        }
    }
}

// =====================================================================
// Mid path (ws in [72,96) MB): exact R6 winner (measured 273us).
// =====================================================================
__global__ __launch_bounds__(256) void gptq_transpose(
    const int* __restrict__ QW, int* __restrict__ QWt)
{
    __shared__ int tile[64][65];
    const u32 bkq = blockIdx.x, bn = blockIdx.y;
    const u32 t = threadIdx.x;
    const u32 r = t >> 4, c4 = (t & 15) * 4;
#pragma unroll
    for (int p = 0; p < 4; ++p) {
        const u32 row = p * 16 + r;
        const int4 v = *(const int4*)(QW + (u64)(bn * 64 + row) * 512
                                         + bkq * 64 + c4);
        tile[row][c4 + 0] = v.x; tile[row][c4 + 1] = v.y;
        tile[row][c4 + 2] = v.z; tile[row][c4 + 3] = v.w;
    }
    __syncthreads();
#pragma unroll
    for (int p = 0; p < 4; ++p) {
        const u32 kql = p * 16 + r;
        int4 v;
        v.x = tile[c4 + 0][kql]; v.y = tile[c4 + 1][kql];
        v.z = tile[c4 + 2][kql]; v.w = tile[c4 + 3][kql];
        *(int4*)(QWt + (u64)(bkq * 64 + kql) * 4096 + bn * 64 + c4) = v;
    }
}

__global__ __launch_bounds__(256, 2) void gptq_gemm_dma(
    const u16* __restrict__ Xh, const int* __restrict__ QWt,
    const int* __restrict__ QZ, const float* __restrict__ SC,
    const float* __restrict__ BIAS, float* __restrict__ Y)
{
    constexpr int N = 4096, NT = 64;
    __shared__ __align__(16) u16 Alds[2][128 * 64];
    const int tid = threadIdx.x, lane = tid & 63, wid = tid >> 6;
    const int mt = blockIdx.x, m0 = mt * 128, n0 = blockIdx.y * 256;
    f32x4 acc[8][4];
#pragma unroll
    for (int i = 0; i < 8; i++)
#pragma unroll
        for (int j = 0; j < 4; j++) acc[i][j] = (f32x4){0.f, 0.f, 0.f, 0.f};
    const int fr = lane & 15, quad = lane >> 4, fr7 = fr & 7;
    const char* xsrc = (const char*)Xh + (((u64)mt * NT) << 14)
                     + wid * 4096 + lane * 16;
    const int nbase = n0 + wid * 64 + fr;
    const char* QWtB = (const char*)QWt;
    const u64 qtbase = (u64)((u32)(quad * 4096 + nbase) * 4u);
    int bq[2][8];
    float sf_st[4];
    int zw_st[4];
    f16x2 cs[4], cz[4];
    const int zsh = fr7 * 4;
    auto STAGE = [&](int buf, int t) {
        const char* s = xsrc + ((u64)t << 14);
        char* d = (char*)&Alds[buf][0] + wid * 4096;
#pragma unroll
        for (int i = 0; i < 4; i++) load_lds16(s + i * 1024, d + i * 1024);
    };
    auto FETCH_B = [&](int t, int nb) {
        const char* p = QWtB + ((u64)t << 17) + qtbase;
#pragma unroll
        for (int ni = 0; ni < 4; ni++) {
            bq[nb][ni * 2 + 0] = *(const int*)(p + ni * 64);
            bq[nb][ni * 2 + 1] = *(const int*)(p + 65536 + ni * 64);
        }
    };
    auto FETCH_SZ = [&](int g) {
#pragma unroll
        for (int ni = 0; ni < 4; ni++) {
            sf_st[ni] = SC[g * N + nbase + ni * 16];
            zw_st[ni] = QZ[g * (N / 8) + ((nbase + ni * 16) >> 3)];
        }
    };
    auto CONV_SZ = [&]() {
#pragma unroll
        for (int ni = 0; ni < 4; ni++) {
            const int z = (zw_st[ni] >> zsh) & 0xF;
            const _Float16 hs = (_Float16)sf_st[ni];
            const _Float16 hz = (_Float16)(float)(1024 + z);
            cs[ni] = (f16x2){hs, hs};
            cz[ni] = (f16x2){hz, hz};
        }
    };
    auto COMPUTE = [&](int buf, int nb) {
#pragma unroll
        for (int ks = 0; ks < 2; ks++) {
            f16x8 bfr[4];
#pragma unroll
            for (int ni = 0; ni < 4; ni++)
                bfr[ni] = unpack_dq((u32)bq[nb][ni * 2 + ks], cz[ni], cs[ni]);
            const int gsw = ((ks * 4 + quad) ^ fr7) * 8;
            __builtin_amdgcn_s_setprio(1);
#pragma unroll
            for (int mi = 0; mi < 8; mi++) {
                const f16x8 af =
                    *(const f16x8*)(&Alds[buf][(mi * 16 + fr) * 64 + gsw]);
#pragma unroll
                for (int ni = 0; ni < 4; ni++)
                    acc[mi][ni] = __builtin_amdgcn_mfma_f32_16x16x32_f16(
                        af, bfr[ni], acc[mi][ni], 0, 0, 0);
            }
            __builtin_amdgcn_s_setprio(0);
        }
    };
    FETCH_B(0, 0);
    FETCH_SZ(0);
    STAGE(0, 0);
    STAGE(1, 1);
    CONV_SZ();
    asm volatile("s_waitcnt vmcnt(4)\n\ts_barrier" ::: "memory");
    for (int t = 0; t <= 60; t += 2) {
        FETCH_B(t + 1, 1);
        FETCH_SZ((t >> 1) + 1);
        COMPUTE(0, 0);
        asm volatile("s_barrier" ::: "memory");
        STAGE(0, t + 2);
        asm volatile("s_waitcnt vmcnt(20)\n\ts_barrier" ::: "memory");
        FETCH_B(t + 2, 0);
        COMPUTE(1, 1);
        CONV_SZ();
        asm volatile("s_barrier" ::: "memory");
        STAGE(1, t + 3);
        asm volatile("s_waitcnt vmcnt(12)\n\ts_barrier" ::: "memory");
    }
    FETCH_B(63, 1);
    COMPUTE(0, 0);
    asm volatile("s_waitcnt vmcnt(8)\n\ts_barrier" ::: "memory");
    COMPUTE(1, 1);
    const int cn = lane & 15, q4r = quad * 4;
#pragma unroll
    for (int ni = 0; ni < 4; ni++) {
        const int col = n0 + wid * 64 + ni * 16 + cn;
        const float bz = BIAS[col];
#pragma unroll
        for (int mi = 0; mi < 8; mi++) {
            const int rbase = m0 + mi * 16 + q4r;
#pragma unroll
            for (int r = 0; r < 4; r++)
                Y[(u64)(rbase + r) * N + col] = acc[mi][ni][r] + bz;
        }
    }
}

// =====================================================================
// Fallback (no ws): R1's verified kernel, unchanged (original inputs).
// =====================================================================
__global__ __launch_bounds__(256, 2) void gptq_gemm_fb(
    const float* __restrict__ X, const int* __restrict__ QW,
    const int* __restrict__ QZ, const float* __restrict__ SC,
    const float* __restrict__ BIAS, float* __restrict__ Y)
{
    constexpr int N = 4096, K = 4096, KB = 512, NT = 64;
    __shared__ __align__(16) u16 Alds[2][128 * 64];
    __shared__ __align__(16) u16 Blds[2][128 * 64];
    const int tid = threadIdx.x, lane = tid & 63, wid = tid >> 6;
    const int m0 = blockIdx.x * 128, n0 = blockIdx.y * 128;
    f32x4 acc[4][4];
#pragma unroll
    for (int i = 0; i < 4; i++)
#pragma unroll
        for (int j = 0; j < 4; j++) acc[i][j] = (f32x4){0.f, 0.f, 0.f, 0.f};
    const int wm = (wid >> 1) * 64, wn = (wid & 1) * 64;
    const int lrowA = tid >> 3;
    const float* gA = X + (u64)(m0 + lrowA) * K + (tid & 7) * 8;
    const int sA = ((tid & 7) ^ (lrowA & 7)) * 8;
    const int nl = tid >> 1, kq0 = (tid & 1) * 4;
    const int nglob = n0 + nl;
    const int* qrow = QW + (u64)nglob * KB;
    const int nl7 = nl & 7, zsh = (nglob & 7) * 4;
    const float* scp = SC + nglob;
    const int* qzp = QZ + (nglob >> 3);
    const int fr = lane & 15, quad = lane >> 4, fr7 = fr & 7;
    float4 af32[8];
    int4 q4;
    float sf;
    int zw;
    auto FETCH = [&](int t) {
        const int kt = t * 64;
#pragma unroll
        for (int i = 0; i < 4; i++) {
            const float* pa = gA + (u64)i * 32 * K + kt;
            af32[2 * i] = *(const float4*)pa;
            af32[2 * i + 1] = *(const float4*)(pa + 4);
        }
        q4 = *(const int4*)(qrow + (kt >> 3) + kq0);
        const int g = t >> 1;
        sf = scp[g * N];
        zw = qzp[g * (N / 8)];
    };
    auto STORE = [&](int buf) {
#pragma unroll
        for (int i = 0; i < 4; i++) {
            const float4 f0 = af32[2 * i], f1 = af32[2 * i + 1];
            uint4 w;
            w.x = cvt_pk(f0.x, f1.x); w.y = cvt_pk(f0.y, f1.y);
            w.z = cvt_pk(f0.z, f1.z); w.w = cvt_pk(f0.w, f1.w);
            *(uint4*)(&Alds[buf][(i * 32 + lrowA) * 64 + sA]) = w;
        }
        const int z = (zw >> zsh) & 0xF;
        const _Float16 hs = (_Float16)sf;
        const _Float16 hz = (_Float16)(float)(1024 + z);
        const f16x2 cs2 = {hs, hs}, cz2 = {hz, hz};
        const int qv[4] = {q4.x, q4.y, q4.z, q4.w};
#pragma unroll
        for (int c = 0; c < 4; c++) {
            const f16x8 wv = unpack_dq((u32)qv[c], cz2, cs2);
            const int gran = ((kq0 + c) ^ nl7) * 8;
            *(f16x8*)(&Blds[buf][nl * 64 + gran]) = wv;
        }
    };
    auto COMPUTE = [&](int buf) {
#pragma unroll
        for (int ks = 0; ks < 2; ks++) {
            const int gsw = ((ks * 4 + quad) ^ fr7) * 8;
            f16x8 af[4], bfr[4];
#pragma unroll
            for (int i = 0; i < 4; i++)
                af[i] = *(const f16x8*)(&Alds[buf][(wm + i * 16 + fr) * 64 + gsw]);
#pragma unroll
            for (int i = 0; i < 4; i++)
                bfr[i] = *(const f16x8*)(&Blds[buf][(wn + i * 16 + fr) * 64 + gsw]);
#pragma unroll
            for (int mi = 0; mi < 4; mi++)
#pragma unroll
                for (int ni = 0; ni < 4; ni++)
                    acc[mi][ni] = __builtin_amdgcn_mfma_f32_16x16x32_f16(
                        af[mi], bfr[ni], acc[mi][ni], 0, 0, 0);
        }
    };
    FETCH(0); STORE(0); __syncthreads();
#pragma unroll 2
    for (int t = 0; t < NT; ++t) {
        const int cur = t & 1;
        if (t + 1 < NT) FETCH(t + 1);
        COMPUTE(cur);
        if (t + 1 < NT) STORE(cur ^ 1);
        __syncthreads();
    }
    const int cn = lane & 15, q4r = quad * 4;
#pragma unroll
    for (int ni = 0; ni < 4; ni++) {
        const int col = n0 + wn + ni * 16 + cn;
        const float bz = BIAS[col];
#pragma unroll
        for (int mi = 0; mi < 4; mi++) {
            const int rbase = m0 + wm + mi * 16 + q4r;
#pragma unroll
            for (int r = 0; r < 4; r++)
                Y[(u64)(rbase + r) * N + col] = acc[mi][ni][r] + bz;
        }
    }
}

extern "C" void kernel_launch(void* const* d_in, const int* in_sizes, int n_in,
                              void* d_out, int out_size, void* d_ws, size_t ws_size,
                              hipStream_t stream) {
    const float* X    = (const float*)d_in[0];   // x       [2,4096,4096] f32
    const int*   QW   = (const int*)d_in[1];     // qweight [4096,512] int32
    const int*   QZ   = (const int*)d_in[2];     // qzeros  [32,512] int32
    const float* SC   = (const float*)d_in[3];   // scales  [32,4096] f32
    const float* BIAS = (const float*)d_in[4];   // bias    [4096] f32
    float* Y = (float*)d_out;                    // [8192,4096] f32

    const size_t needXh = (size_t)8192 * 4096 * sizeof(u16);       // 64 MiB
    const size_t needNew = needXh + (size_t)4096 * 4096 * 2;       // + 32 MiB
    const size_t needMid = needXh + (size_t)512 * 4096 * 4;        // + 8 MiB
    if (ws_size >= needNew) {
        u16* Xh = (u16*)d_ws;
        u16* Bt = (u16*)((char*)d_ws + needXh);
        gptq_prepass<<<4096, 256, 0, stream>>>(X, Xh);
        gptq_dequantB<<<dim3(8, 64), 256, 0, stream>>>(QW, QZ, SC, Bt);
        dim3 grid(64, 16, 1);                               // M/128 x N/256
        gptq_gemm_dq<<<grid, 256, 0, stream>>>(Xh, Bt, BIAS, Y);
    } else if (ws_size >= needMid) {
        u16* Xh  = (u16*)d_ws;
        int* QWt = (int*)((char*)d_ws + needXh);
        gptq_prepass<<<4096, 256, 0, stream>>>(X, Xh);
        gptq_transpose<<<dim3(8, 64), 256, 0, stream>>>(QW, QWt);
        dim3 grid(64, 16, 1);                               // M/128 x N/256
        gptq_gemm_dma<<<grid, 256, 0, stream>>>(Xh, QWt, QZ, SC, BIAS, Y);
    } else {
        dim3 grid(64, 32, 1);                               // M/128 x N/128
        gptq_gemm_fb<<<grid, 256, 0, stream>>>(X, QW, QZ, SC, BIAS, Y);
    }
}